// Round 1
// baseline (1272.563 us; speedup 1.0000x reference)
//
#include <hip/hip_runtime.h>
#include <math.h>

#define NN 20000   // nodes
#define NE 480000  // edges
#define NB 4       // batch
#define ND 32      // dim
#define NR 474     // relations
#define NL 3       // layers
#define NT 64      // tails

// ---------------- CSR build ----------------
__global__ __launch_bounds__(256) void count_kernel(const int* __restrict__ dst,
                                                    int* __restrict__ indeg) {
    int e = blockIdx.x * blockDim.x + threadIdx.x;
    if (e < NE) atomicAdd(&indeg[dst[e]], 1);
}

__global__ __launch_bounds__(1024) void scan_kernel(const int* __restrict__ indeg,
                                                    int* __restrict__ offsets) {
    __shared__ int sums[1024];
    int tid = threadIdx.x;
    const int chunk = (NN + 1023) / 1024;  // 20
    int start = tid * chunk;
    int end = start + chunk; if (end > NN) end = NN; if (start > NN) start = NN;
    int s = 0;
    for (int i = start; i < end; ++i) s += indeg[i];
    sums[tid] = s;
    __syncthreads();
    for (int off = 1; off < 1024; off <<= 1) {
        int v = (tid >= off) ? sums[tid - off] : 0;
        __syncthreads();
        sums[tid] += v;
        __syncthreads();
    }
    int base = (tid > 0) ? sums[tid - 1] : 0;
    for (int i = start; i < end; ++i) { offsets[i] = base; base += indeg[i]; }
    if (tid == 1023) offsets[NN] = sums[1023];
}

__global__ __launch_bounds__(256) void scatter_kernel(const int* __restrict__ src,
                                                      const int* __restrict__ dst,
                                                      const int* __restrict__ etype,
                                                      const int* __restrict__ offsets,
                                                      int* __restrict__ cursor,
                                                      int2* __restrict__ csr) {
    int e = blockIdx.x * blockDim.x + threadIdx.x;
    if (e < NE) {
        int dn = dst[e];
        int pos = atomicAdd(&cursor[dn], 1);
        csr[offsets[dn] + pos] = make_int2(src[e], etype[e]);
    }
}

// ---------------- degree-scale sum ----------------
__global__ __launch_bounds__(256) void logsum_kernel(const int* __restrict__ indeg,
                                                     float* __restrict__ ssum) {
    int n = blockIdx.x * blockDim.x + threadIdx.x;
    float v = (n < NN) ? logf((float)(indeg[n] + 2)) : 0.f;  // log(deg+1), deg = indeg+1
    #pragma unroll
    for (int off = 32; off > 0; off >>= 1) v += __shfl_down(v, off, 64);
    if ((threadIdx.x & 63) == 0) atomicAdd(ssum, v);
}

// ---------------- boundary init ----------------
__global__ void init_hidden_kernel(float* __restrict__ h0, const int* __restrict__ h_index,
                                   const int* __restrict__ r_index,
                                   const float* __restrict__ qw) {
    int i = threadIdx.x;  // 128 = NB*ND threads
    int b = i >> 5, d = i & 31;
    h0[(size_t)b * NN * ND + (size_t)h_index[b] * ND + d] = qw[r_index[b] * ND + d];
}

// ---------------- per-layer relation embeddings: rel[l][b][r][d] ----------------
__global__ __launch_bounds__(256) void rel_kernel(const float* __restrict__ qw,
                                                  const int* __restrict__ r_index,
                                                  const float* __restrict__ rlw,
                                                  float* __restrict__ rel) {
    int i = blockIdx.x * blockDim.x + threadIdx.x;
    if (i >= NL * NB * NR * ND) return;
    int d = i & (ND - 1);
    int r = (i / ND) % NR;
    int b = (i / (ND * NR)) % NB;
    int l = i / (ND * NR * NB);
    const float* q = qw + r_index[b] * ND;
    const float* w = rlw + (size_t)l * ND * NR * ND + (size_t)r * ND + d;
    float acc = 0.f;
    #pragma unroll
    for (int k = 0; k < ND; ++k) acc += q[k] * w[(size_t)k * NR * ND];
    rel[i] = acc;
}

// ---------------- fused aggregate + PNA + update + residual, one layer ----------------
__global__ __launch_bounds__(256) void agg_update_kernel(
    const float* __restrict__ hin, float* __restrict__ hout,
    const float* __restrict__ rel,               // [B][R][D] for this layer
    const int* __restrict__ offsets, const int2* __restrict__ csr,
    const float* __restrict__ scalesum,
    const int* __restrict__ h_index, const int* __restrict__ r_index,
    const float* __restrict__ qw,
    const float* __restrict__ Wl, const float* __restrict__ bl) {
    __shared__ float ldsW[13 * ND * ND];   // 13312 floats = 52 KiB
    __shared__ float feats[8][5][ND];      // h, mean, max, min, std
    int tid = threadIdx.x;
    for (int i = tid; i < 13 * ND * ND; i += 256) ldsW[i] = Wl[i];

    int g = tid >> 5, d = tid & 31;
    int idx = blockIdx.x * 8 + g;          // in [0, NB*NN)
    int b = idx / NN, n = idx - b * NN;
    const float* hb = hin + (size_t)b * NN * ND;
    const float* relb = rel + (size_t)b * NR * ND;

    float bm = (n == h_index[b]) ? qw[r_index[b] * ND + d] : 0.f;  // boundary self-msg
    float s = bm, ss = bm * bm, mx = bm, mn = bm;
    int beg = offsets[n], end = offsets[n + 1];
    for (int e = beg; e < end; ++e) {
        int2 se = csr[e];
        float m = hb[(size_t)se.x * ND + d] * relb[(size_t)se.y * ND + d];
        s += m; ss += m * m; mx = fmaxf(mx, m); mn = fminf(mn, m);
    }
    float degf = (float)(end - beg + 1);
    float inv = 1.0f / degf;
    float mean = s * inv;
    float stdv = sqrtf(fmaxf(ss * inv - mean * mean, 0.f));
    float h = hb[(size_t)n * ND + d];
    feats[g][0][d] = h;  feats[g][1][d] = mean; feats[g][2][d] = mx;
    feats[g][3][d] = mn; feats[g][4][d] = stdv;
    __syncthreads();

    float scl = logf(degf + 1.0f) * ((float)NN / *scalesum);  // normalized scale
    float sc1 = scl, sc2 = 1.0f / fmaxf(scl, 1e-2f);

    float acc = bl[d];
    const float* F0 = &feats[g][0][0];
    #pragma unroll 8
    for (int dd = 0; dd < ND; ++dd) acc += F0[dd] * ldsW[dd * ND + d];
    int k = ND;
    for (int js = 0; js < 3; ++js) {
        float scj = (js == 0) ? 1.0f : ((js == 1) ? sc1 : sc2);
        for (int f = 1; f <= 4; ++f) {
            const float* Ff = &feats[g][f][0];
            #pragma unroll 8
            for (int dd = 0; dd < ND; ++dd) { acc += (Ff[dd] * scj) * ldsW[k * ND + d]; ++k; }
        }
    }
    hout[(size_t)b * NN * ND + (size_t)n * ND + d] = fmaxf(acc, 0.f) + h;
}

// ---------------- final MLP scorer ----------------
__global__ __launch_bounds__(256) void score_kernel(
    const float* __restrict__ hidden, const int* __restrict__ t_index,
    const int* __restrict__ r_index, const float* __restrict__ qw,
    const float* __restrict__ w1, const float* __restrict__ b1,
    const float* __restrict__ w2, const float* __restrict__ b2,
    float* __restrict__ out) {
    int i = blockIdx.x * blockDim.x + threadIdx.x;
    if (i >= NB * NT) return;
    int b = i / NT;
    int node = t_index[i];
    float feat[2 * ND];
    #pragma unroll
    for (int d = 0; d < ND; ++d)
        feat[d] = hidden[(size_t)b * NN * ND + (size_t)node * ND + d];
    const float* q = qw + r_index[b] * ND;
    #pragma unroll
    for (int d = 0; d < ND; ++d) feat[ND + d] = q[d];
    float acc2 = b2[0];
    for (int j = 0; j < 2 * ND; ++j) {
        float a = b1[j];
        #pragma unroll
        for (int kk = 0; kk < 2 * ND; ++kk) a += feat[kk] * w1[kk * 2 * ND + j];
        acc2 += fmaxf(a, 0.f) * w2[j];
    }
    out[i] = acc2;
}

extern "C" void kernel_launch(void* const* d_in, const int* in_sizes, int n_in,
                              void* d_out, int out_size, void* d_ws, size_t ws_size,
                              hipStream_t stream) {
    (void)in_sizes; (void)n_in; (void)out_size; (void)ws_size;
    const int* edge_index = (const int*)d_in[0];     // [2][E]
    const int* edge_type  = (const int*)d_in[1];     // [E]
    const int* h_index    = (const int*)d_in[2];     // [B]
    const int* r_index    = (const int*)d_in[3];     // [B]
    const int* t_index    = (const int*)d_in[4];     // [B][T]
    const float* query_weight = (const float*)d_in[5];  // [R][D]
    const float* rel_lin_w    = (const float*)d_in[6];  // [L][D][R*D]
    const float* layer_w      = (const float*)d_in[7];  // [L][13D][D]
    const float* layer_b      = (const float*)d_in[8];  // [L][D]
    const float* mlp_w1 = (const float*)d_in[9];
    const float* mlp_b1 = (const float*)d_in[10];
    const float* mlp_w2 = (const float*)d_in[11];
    const float* mlp_b2 = (const float*)d_in[12];
    float* out = (float*)d_out;

    const int* src = edge_index;
    const int* dst = edge_index + NE;

    char* wsp = (char*)d_ws;
    size_t off = 0;
    auto alloc = [&](size_t bytes) -> void* {
        void* p = wsp + off;
        off += (bytes + 255) & ~(size_t)255;
        return p;
    };
    float* h0      = (float*)alloc(sizeof(float) * NB * NN * ND);
    float* h1      = (float*)alloc(sizeof(float) * NB * NN * ND);
    float* rel     = (float*)alloc(sizeof(float) * NL * NB * NR * ND);
    int2*  csr     = (int2*)alloc(sizeof(int2) * NE);
    int*   offsets = (int*)alloc(sizeof(int) * (NN + 1));
    int*   cursor  = (int*)alloc(sizeof(int) * NN);
    int*   indeg   = (int*)alloc(sizeof(int) * NN);
    float* ssum    = (float*)alloc(256);

    hipMemsetAsync(indeg, 0, sizeof(int) * NN, stream);
    hipMemsetAsync(cursor, 0, sizeof(int) * NN, stream);
    hipMemsetAsync(ssum, 0, sizeof(float), stream);
    hipMemsetAsync(h0, 0, sizeof(float) * NB * NN * ND, stream);

    count_kernel<<<(NE + 255) / 256, 256, 0, stream>>>(dst, indeg);
    scan_kernel<<<1, 1024, 0, stream>>>(indeg, offsets);
    scatter_kernel<<<(NE + 255) / 256, 256, 0, stream>>>(src, dst, edge_type, offsets, cursor, csr);
    logsum_kernel<<<(NN + 255) / 256, 256, 0, stream>>>(indeg, ssum);
    init_hidden_kernel<<<1, NB * ND, 0, stream>>>(h0, h_index, r_index, query_weight);

    int rel_total = NL * NB * NR * ND;
    rel_kernel<<<(rel_total + 255) / 256, 256, 0, stream>>>(query_weight, r_index, rel_lin_w, rel);

    float* hin = h0;
    float* hout = h1;
    for (int l = 0; l < NL; ++l) {
        agg_update_kernel<<<NB * NN / 8, 256, 0, stream>>>(
            hin, hout, rel + (size_t)l * NB * NR * ND,
            offsets, csr, ssum, h_index, r_index, query_weight,
            layer_w + (size_t)l * 13 * ND * ND, layer_b + (size_t)l * ND);
        float* t = hin; hin = hout; hout = t;
    }
    // final hidden is in `hin`

    score_kernel<<<1, 256, 0, stream>>>(hin, t_index, r_index, query_weight,
                                        mlp_w1, mlp_b1, mlp_w2, mlp_b2, out);
}

// Round 2
// 573.606 us; speedup vs baseline: 2.2185x; 2.2185x over previous
//
#include <hip/hip_runtime.h>
#include <math.h>

#define NN 20000   // nodes
#define NE 480000  // edges
#define NB 4       // batch
#define ND 32      // dim
#define NR 474     // relations
#define NL 3       // layers
#define NT 64      // tails

// ---------------- CSR build ----------------
__global__ __launch_bounds__(256) void count_kernel(const int* __restrict__ dst,
                                                    int* __restrict__ indeg) {
    int e = blockIdx.x * blockDim.x + threadIdx.x;
    if (e < NE) atomicAdd(&indeg[dst[e]], 1);
}

__global__ __launch_bounds__(1024) void scan_kernel(const int* __restrict__ indeg,
                                                    int* __restrict__ offsets) {
    __shared__ int sums[1024];
    int tid = threadIdx.x;
    const int chunk = (NN + 1023) / 1024;  // 20
    int start = tid * chunk;
    int end = start + chunk; if (end > NN) end = NN; if (start > NN) start = NN;
    int s = 0;
    for (int i = start; i < end; ++i) s += indeg[i];
    sums[tid] = s;
    __syncthreads();
    for (int off = 1; off < 1024; off <<= 1) {
        int v = (tid >= off) ? sums[tid - off] : 0;
        __syncthreads();
        sums[tid] += v;
        __syncthreads();
    }
    int base = (tid > 0) ? sums[tid - 1] : 0;
    for (int i = start; i < end; ++i) { offsets[i] = base; base += indeg[i]; }
    if (tid == 1023) offsets[NN] = sums[1023];
}

__global__ __launch_bounds__(256) void scatter_kernel(const int* __restrict__ src,
                                                      const int* __restrict__ dst,
                                                      const int* __restrict__ etype,
                                                      const int* __restrict__ offsets,
                                                      int* __restrict__ cursor,
                                                      int2* __restrict__ csr) {
    int e = blockIdx.x * blockDim.x + threadIdx.x;
    if (e < NE) {
        int dn = dst[e];
        int pos = atomicAdd(&cursor[dn], 1);
        csr[offsets[dn] + pos] = make_int2(src[e], etype[e]);
    }
}

// ---------------- degree-scale sum ----------------
__global__ __launch_bounds__(256) void logsum_kernel(const int* __restrict__ indeg,
                                                     float* __restrict__ ssum) {
    int n = blockIdx.x * blockDim.x + threadIdx.x;
    float v = (n < NN) ? logf((float)(indeg[n] + 2)) : 0.f;  // log(deg+1), deg = indeg+1
    #pragma unroll
    for (int off = 32; off > 0; off >>= 1) v += __shfl_down(v, off, 64);
    if ((threadIdx.x & 63) == 0) atomicAdd(ssum, v);
}

// ---------------- boundary init ----------------
__global__ void init_hidden_kernel(float* __restrict__ h0, const int* __restrict__ h_index,
                                   const int* __restrict__ r_index,
                                   const float* __restrict__ qw) {
    int i = threadIdx.x;  // 128 = NB*ND threads
    int b = i >> 5, d = i & 31;
    h0[(size_t)b * NN * ND + (size_t)h_index[b] * ND + d] = qw[r_index[b] * ND + d];
}

// ---------------- per-layer relation embeddings: rel[l][b][r][d] ----------------
__global__ __launch_bounds__(256) void rel_kernel(const float* __restrict__ qw,
                                                  const int* __restrict__ r_index,
                                                  const float* __restrict__ rlw,
                                                  float* __restrict__ rel) {
    int i = blockIdx.x * blockDim.x + threadIdx.x;
    if (i >= NL * NB * NR * ND) return;
    int d = i & (ND - 1);
    int r = (i / ND) % NR;
    int b = (i / (ND * NR)) % NB;
    int l = i / (ND * NR * NB);
    const float* q = qw + r_index[b] * ND;
    const float* w = rlw + (size_t)l * ND * NR * ND + (size_t)r * ND + d;
    float acc = 0.f;
    #pragma unroll
    for (int k = 0; k < ND; ++k) acc += q[k] * w[(size_t)k * NR * ND];
    rel[i] = acc;
}

// ---------------- fused aggregate + PNA + update + residual, one layer ----------------
// 512 threads = 16 node-groups of 32 lanes. LDS: 52K (W) + 10K (feats) = 62K
// -> 2 blocks/CU = 16 waves/CU. Edge loop unrolled x4 for gather ILP.
__global__ __launch_bounds__(512, 4) void agg_update_kernel(
    const float* __restrict__ hin, float* __restrict__ hout,
    const float* __restrict__ rel,               // [B][R][D] for this layer
    const int* __restrict__ offsets, const int2* __restrict__ csr,
    const float* __restrict__ scalesum,
    const int* __restrict__ h_index, const int* __restrict__ r_index,
    const float* __restrict__ qw,
    const float* __restrict__ Wl, const float* __restrict__ bl) {
    __shared__ float ldsW[13 * ND * ND];   // 13312 floats = 52 KiB
    __shared__ float feats[16][5][ND];     // h, mean, max, min, std
    int tid = threadIdx.x;
    for (int i = tid; i < 13 * ND * ND; i += 512) ldsW[i] = Wl[i];

    int g = tid >> 5, d = tid & 31;
    int idx = blockIdx.x * 16 + g;         // in [0, NB*NN)
    int b = idx / NN, n = idx - b * NN;
    const float* hb = hin + (size_t)b * NN * ND;
    const float* relb = rel + (size_t)b * NR * ND;

    float bm = (n == h_index[b]) ? qw[r_index[b] * ND + d] : 0.f;  // boundary self-msg
    float s = bm, ss = bm * bm, mx = bm, mn = bm;
    int beg = offsets[n], end = offsets[n + 1];
    int e = beg;
    for (; e + 4 <= end; e += 4) {
        int2 a0 = csr[e + 0];
        int2 a1 = csr[e + 1];
        int2 a2 = csr[e + 2];
        int2 a3 = csr[e + 3];
        float h0 = hb[(size_t)a0.x * ND + d], r0 = relb[(size_t)a0.y * ND + d];
        float h1 = hb[(size_t)a1.x * ND + d], r1 = relb[(size_t)a1.y * ND + d];
        float h2 = hb[(size_t)a2.x * ND + d], r2 = relb[(size_t)a2.y * ND + d];
        float h3 = hb[(size_t)a3.x * ND + d], r3 = relb[(size_t)a3.y * ND + d];
        float m0 = h0 * r0, m1 = h1 * r1, m2 = h2 * r2, m3 = h3 * r3;
        s += (m0 + m1) + (m2 + m3);
        ss += (m0 * m0 + m1 * m1) + (m2 * m2 + m3 * m3);
        mx = fmaxf(mx, fmaxf(fmaxf(m0, m1), fmaxf(m2, m3)));
        mn = fminf(mn, fminf(fminf(m0, m1), fminf(m2, m3)));
    }
    for (; e < end; ++e) {
        int2 se = csr[e];
        float m = hb[(size_t)se.x * ND + d] * relb[(size_t)se.y * ND + d];
        s += m; ss += m * m; mx = fmaxf(mx, m); mn = fminf(mn, m);
    }
    float degf = (float)(end - beg + 1);
    float inv = 1.0f / degf;
    float mean = s * inv;
    float stdv = sqrtf(fmaxf(ss * inv - mean * mean, 0.f));
    float h = hb[(size_t)n * ND + d];
    feats[g][0][d] = h;  feats[g][1][d] = mean; feats[g][2][d] = mx;
    feats[g][3][d] = mn; feats[g][4][d] = stdv;
    __syncthreads();

    float scl = logf(degf + 1.0f) * ((float)NN / *scalesum);  // normalized scale
    float sc1 = scl, sc2 = 1.0f / fmaxf(scl, 1e-2f);

    float acc = bl[d];
    const float* F0 = &feats[g][0][0];
    #pragma unroll 8
    for (int dd = 0; dd < ND; ++dd) acc += F0[dd] * ldsW[dd * ND + d];
    int k = ND;
    for (int js = 0; js < 3; ++js) {
        float scj = (js == 0) ? 1.0f : ((js == 1) ? sc1 : sc2);
        for (int f = 1; f <= 4; ++f) {
            const float* Ff = &feats[g][f][0];
            #pragma unroll 8
            for (int dd = 0; dd < ND; ++dd) { acc += (Ff[dd] * scj) * ldsW[k * ND + d]; ++k; }
        }
    }
    hout[(size_t)b * NN * ND + (size_t)n * ND + d] = fmaxf(acc, 0.f) + h;
}

// ---------------- final MLP scorer ----------------
__global__ __launch_bounds__(256) void score_kernel(
    const float* __restrict__ hidden, const int* __restrict__ t_index,
    const int* __restrict__ r_index, const float* __restrict__ qw,
    const float* __restrict__ w1, const float* __restrict__ b1,
    const float* __restrict__ w2, const float* __restrict__ b2,
    float* __restrict__ out) {
    int i = blockIdx.x * blockDim.x + threadIdx.x;
    if (i >= NB * NT) return;
    int b = i / NT;
    int node = t_index[i];
    float feat[2 * ND];
    #pragma unroll
    for (int d = 0; d < ND; ++d)
        feat[d] = hidden[(size_t)b * NN * ND + (size_t)node * ND + d];
    const float* q = qw + r_index[b] * ND;
    #pragma unroll
    for (int d = 0; d < ND; ++d) feat[ND + d] = q[d];
    float acc2 = b2[0];
    for (int j = 0; j < 2 * ND; ++j) {
        float a = b1[j];
        #pragma unroll
        for (int kk = 0; kk < 2 * ND; ++kk) a += feat[kk] * w1[kk * 2 * ND + j];
        acc2 += fmaxf(a, 0.f) * w2[j];
    }
    out[i] = acc2;
}

extern "C" void kernel_launch(void* const* d_in, const int* in_sizes, int n_in,
                              void* d_out, int out_size, void* d_ws, size_t ws_size,
                              hipStream_t stream) {
    (void)in_sizes; (void)n_in; (void)out_size; (void)ws_size;
    const int* edge_index = (const int*)d_in[0];     // [2][E]
    const int* edge_type  = (const int*)d_in[1];     // [E]
    const int* h_index    = (const int*)d_in[2];     // [B]
    const int* r_index    = (const int*)d_in[3];     // [B]
    const int* t_index    = (const int*)d_in[4];     // [B][T]
    const float* query_weight = (const float*)d_in[5];  // [R][D]
    const float* rel_lin_w    = (const float*)d_in[6];  // [L][D][R*D]
    const float* layer_w      = (const float*)d_in[7];  // [L][13D][D]
    const float* layer_b      = (const float*)d_in[8];  // [L][D]
    const float* mlp_w1 = (const float*)d_in[9];
    const float* mlp_b1 = (const float*)d_in[10];
    const float* mlp_w2 = (const float*)d_in[11];
    const float* mlp_b2 = (const float*)d_in[12];
    float* out = (float*)d_out;

    const int* src = edge_index;
    const int* dst = edge_index + NE;

    char* wsp = (char*)d_ws;
    size_t off = 0;
    auto alloc = [&](size_t bytes) -> void* {
        void* p = wsp + off;
        off += (bytes + 255) & ~(size_t)255;
        return p;
    };
    float* h0      = (float*)alloc(sizeof(float) * NB * NN * ND);
    float* h1      = (float*)alloc(sizeof(float) * NB * NN * ND);
    float* rel     = (float*)alloc(sizeof(float) * NL * NB * NR * ND);
    int2*  csr     = (int2*)alloc(sizeof(int2) * NE);
    int*   offsets = (int*)alloc(sizeof(int) * (NN + 1));
    int*   cursor  = (int*)alloc(sizeof(int) * NN);
    int*   indeg   = (int*)alloc(sizeof(int) * NN);
    float* ssum    = (float*)alloc(256);

    hipMemsetAsync(indeg, 0, sizeof(int) * NN, stream);
    hipMemsetAsync(cursor, 0, sizeof(int) * NN, stream);
    hipMemsetAsync(ssum, 0, sizeof(float), stream);
    hipMemsetAsync(h0, 0, sizeof(float) * NB * NN * ND, stream);

    count_kernel<<<(NE + 255) / 256, 256, 0, stream>>>(dst, indeg);
    scan_kernel<<<1, 1024, 0, stream>>>(indeg, offsets);
    scatter_kernel<<<(NE + 255) / 256, 256, 0, stream>>>(src, dst, edge_type, offsets, cursor, csr);
    logsum_kernel<<<(NN + 255) / 256, 256, 0, stream>>>(indeg, ssum);
    init_hidden_kernel<<<1, NB * ND, 0, stream>>>(h0, h_index, r_index, query_weight);

    int rel_total = NL * NB * NR * ND;
    rel_kernel<<<(rel_total + 255) / 256, 256, 0, stream>>>(query_weight, r_index, rel_lin_w, rel);

    float* hin = h0;
    float* hout = h1;
    for (int l = 0; l < NL; ++l) {
        agg_update_kernel<<<NB * NN / 16, 512, 0, stream>>>(
            hin, hout, rel + (size_t)l * NB * NR * ND,
            offsets, csr, ssum, h_index, r_index, query_weight,
            layer_w + (size_t)l * 13 * ND * ND, layer_b + (size_t)l * ND);
        float* t = hin; hin = hout; hout = t;
    }
    // final hidden is in `hin`

    score_kernel<<<1, 256, 0, stream>>>(hin, t_index, r_index, query_weight,
                                        mlp_w1, mlp_b1, mlp_w2, mlp_b2, out);
}

// Round 3
// 535.267 us; speedup vs baseline: 2.3774x; 1.0716x over previous
//
#include <hip/hip_runtime.h>
#include <math.h>

#define NN 20000   // nodes
#define NE 480000  // edges
#define NB 4       // batch
#define ND 32      // dim
#define NR 474     // relations
#define NL 3       // layers
#define NT 64      // tails
#define M_TOT (NB * NN)   // 80000 node-rows

// ---------------- CSR build ----------------
__global__ __launch_bounds__(256) void count_kernel(const int* __restrict__ dst,
                                                    int* __restrict__ indeg) {
    int e = blockIdx.x * blockDim.x + threadIdx.x;
    if (e < NE) atomicAdd(&indeg[dst[e]], 1);
}

__global__ __launch_bounds__(1024) void scan_kernel(const int* __restrict__ indeg,
                                                    int* __restrict__ offsets) {
    __shared__ int sums[1024];
    int tid = threadIdx.x;
    const int chunk = (NN + 1023) / 1024;  // 20
    int start = tid * chunk;
    int end = start + chunk; if (end > NN) end = NN; if (start > NN) start = NN;
    int s = 0;
    for (int i = start; i < end; ++i) s += indeg[i];
    sums[tid] = s;
    __syncthreads();
    for (int off = 1; off < 1024; off <<= 1) {
        int v = (tid >= off) ? sums[tid - off] : 0;
        __syncthreads();
        sums[tid] += v;
        __syncthreads();
    }
    int base = (tid > 0) ? sums[tid - 1] : 0;
    for (int i = start; i < end; ++i) { offsets[i] = base; base += indeg[i]; }
    if (tid == 1023) offsets[NN] = sums[1023];
}

__global__ __launch_bounds__(256) void scatter_kernel(const int* __restrict__ src,
                                                      const int* __restrict__ dst,
                                                      const int* __restrict__ etype,
                                                      const int* __restrict__ offsets,
                                                      int* __restrict__ cursor,
                                                      int2* __restrict__ csr) {
    int e = blockIdx.x * blockDim.x + threadIdx.x;
    if (e < NE) {
        int dn = dst[e];
        int pos = atomicAdd(&cursor[dn], 1);
        csr[offsets[dn] + pos] = make_int2(src[e], etype[e]);
    }
}

// ---------------- degree-scale sum ----------------
__global__ __launch_bounds__(256) void logsum_kernel(const int* __restrict__ indeg,
                                                     float* __restrict__ ssum) {
    int n = blockIdx.x * blockDim.x + threadIdx.x;
    float v = (n < NN) ? logf((float)(indeg[n] + 2)) : 0.f;  // log(deg+1), deg = indeg+1
    #pragma unroll
    for (int off = 32; off > 0; off >>= 1) v += __shfl_down(v, off, 64);
    if ((threadIdx.x & 63) == 0) atomicAdd(ssum, v);
}

// ---------------- boundary init ----------------
__global__ void init_hidden_kernel(float* __restrict__ h0, const int* __restrict__ h_index,
                                   const int* __restrict__ r_index,
                                   const float* __restrict__ qw) {
    int i = threadIdx.x;  // 128 = NB*ND threads
    int b = i >> 5, d = i & 31;
    h0[(size_t)b * NN * ND + (size_t)h_index[b] * ND + d] = qw[r_index[b] * ND + d];
}

// ---------------- per-layer relation embeddings: rel[l][b][r][d] ----------------
__global__ __launch_bounds__(256) void rel_kernel(const float* __restrict__ qw,
                                                  const int* __restrict__ r_index,
                                                  const float* __restrict__ rlw,
                                                  float* __restrict__ rel) {
    int i = blockIdx.x * blockDim.x + threadIdx.x;
    if (i >= NL * NB * NR * ND) return;
    int d = i & (ND - 1);
    int r = (i / ND) % NR;
    int b = (i / (ND * NR)) % NB;
    int l = i / (ND * NR * NB);
    const float* q = qw + r_index[b] * ND;
    const float* w = rlw + (size_t)l * ND * NR * ND + (size_t)r * ND + d;
    float acc = 0.f;
    #pragma unroll
    for (int k = 0; k < ND; ++k) acc += q[k] * w[(size_t)k * NR * ND];
    rel[i] = acc;
}

// ---------------- aggregation + PNA stats -> transposed feature matrix ----------------
// 512 threads = 16 node-groups of 32 lanes. Only 11 KiB LDS -> ~full occupancy.
// Writes At[k][i] (k = 0..159: h(32), mean(32), max(32), min(32), std(32)),
// coalesced 64B rows via LDS transpose. Scalers are applied in gemm_kernel.
__global__ __launch_bounds__(512) void agg_kernel(
    const float* __restrict__ hin, float* __restrict__ At,
    const float* __restrict__ rel,               // [B][R][D] for this layer
    const int* __restrict__ offsets, const int2* __restrict__ csr,
    const int* __restrict__ h_index, const int* __restrict__ r_index,
    const float* __restrict__ qw) {
    __shared__ float tr[160][17];                // +1 pad: conflict-free col writes
    int tid = threadIdx.x;
    int g = tid >> 5, d = tid & 31;
    int idx = blockIdx.x * 16 + g;               // in [0, M_TOT)
    int b = idx / NN, n = idx - b * NN;
    const float* hb = hin + (size_t)b * NN * ND;
    const float* relb = rel + (size_t)b * NR * ND;

    float bm = (n == h_index[b]) ? qw[r_index[b] * ND + d] : 0.f;  // boundary self-msg
    float s = bm, ss = bm * bm, mx = bm, mn = bm;
    int beg = offsets[n], end = offsets[n + 1];
    int e = beg;
    for (; e + 4 <= end; e += 4) {
        int2 a0 = csr[e + 0];
        int2 a1 = csr[e + 1];
        int2 a2 = csr[e + 2];
        int2 a3 = csr[e + 3];
        float h0 = hb[(size_t)a0.x * ND + d], r0 = relb[(size_t)a0.y * ND + d];
        float h1 = hb[(size_t)a1.x * ND + d], r1 = relb[(size_t)a1.y * ND + d];
        float h2 = hb[(size_t)a2.x * ND + d], r2 = relb[(size_t)a2.y * ND + d];
        float h3 = hb[(size_t)a3.x * ND + d], r3 = relb[(size_t)a3.y * ND + d];
        float m0 = h0 * r0, m1 = h1 * r1, m2 = h2 * r2, m3 = h3 * r3;
        s += (m0 + m1) + (m2 + m3);
        ss += (m0 * m0 + m1 * m1) + (m2 * m2 + m3 * m3);
        mx = fmaxf(mx, fmaxf(fmaxf(m0, m1), fmaxf(m2, m3)));
        mn = fminf(mn, fminf(fminf(m0, m1), fminf(m2, m3)));
    }
    for (; e < end; ++e) {
        int2 se = csr[e];
        float m = hb[(size_t)se.x * ND + d] * relb[(size_t)se.y * ND + d];
        s += m; ss += m * m; mx = fmaxf(mx, m); mn = fminf(mn, m);
    }
    float degf = (float)(end - beg + 1);
    float inv = 1.0f / degf;
    float mean = s * inv;
    float stdv = sqrtf(fmaxf(ss * inv - mean * mean, 0.f));
    float h = hb[(size_t)n * ND + d];
    tr[d][g] = h;
    tr[32 + d][g] = mean;
    tr[64 + d][g] = mx;
    tr[96 + d][g] = mn;
    tr[128 + d][g] = stdv;
    __syncthreads();

    int r = tid >> 4, c = tid & 15;
    size_t col = (size_t)blockIdx.x * 16 + c;
    for (int rr = r; rr < 160; rr += 32)
        At[(size_t)rr * M_TOT + col] = tr[rr][c];
}

// ---------------- update GEMM: node-per-lane, W uniform via SGPR ----------------
// out[i][j] = relu( b[j] + sum_k F[k][i]*Weff[k][j] ) + h[i][j]
// Weff rows: 0..31 -> W[0..31] (h block); 32..159 -> W[dd] + sc1*W[dd+128] + sc2*W[dd+256]
__global__ __launch_bounds__(128) void gemm_kernel(
    const float* __restrict__ At, float* __restrict__ hnew,
    const float* __restrict__ W, const float* __restrict__ bias,
    const int* __restrict__ offsets, const float* __restrict__ ssum) {
    __shared__ float tr2[128 * 33];
    int t = threadIdx.x;
    int i = blockIdx.x * 128 + t;                // node-row, grid covers exactly M_TOT
    float acc[32];
    #pragma unroll
    for (int j = 0; j < 32; ++j) acc[j] = 0.f;

    #pragma unroll 2
    for (int dd = 0; dd < 32; ++dd) {
        float a = At[(size_t)dd * M_TOT + i];
        #pragma unroll
        for (int j = 0; j < 32; ++j) acc[j] += a * W[dd * 32 + j];
    }
    int n = i % NN;
    float degf = (float)(offsets[n + 1] - offsets[n] + 1);
    float scl = logf(degf + 1.0f) * ((float)NN / *ssum);
    float sc1 = scl, sc2 = 1.0f / fmaxf(scl, 1e-2f);
    #pragma unroll 2
    for (int dd = 32; dd < 160; ++dd) {
        float a = At[(size_t)dd * M_TOT + i];
        float a1 = a * sc1, a2 = a * sc2;
        #pragma unroll
        for (int j = 0; j < 32; ++j)
            acc[j] += a * W[dd * 32 + j] + a1 * W[(dd + 128) * 32 + j] + a2 * W[(dd + 256) * 32 + j];
    }
    #pragma unroll
    for (int j = 0; j < 32; ++j) {
        float h = At[(size_t)j * M_TOT + i];
        tr2[t * 33 + j] = fmaxf(acc[j] + bias[j], 0.f) + h;
    }
    __syncthreads();
    size_t obase = (size_t)blockIdx.x * 128 * 32;
    #pragma unroll 4
    for (int p = 0; p < 32; ++p) {
        int fl = p * 128 + t;
        hnew[obase + fl] = tr2[(fl >> 5) * 33 + (fl & 31)];
    }
}

// ---------------- final MLP scorer ----------------
__global__ __launch_bounds__(256) void score_kernel(
    const float* __restrict__ hidden, const int* __restrict__ t_index,
    const int* __restrict__ r_index, const float* __restrict__ qw,
    const float* __restrict__ w1, const float* __restrict__ b1,
    const float* __restrict__ w2, const float* __restrict__ b2,
    float* __restrict__ out) {
    int i = blockIdx.x * blockDim.x + threadIdx.x;
    if (i >= NB * NT) return;
    int b = i / NT;
    int node = t_index[i];
    float feat[2 * ND];
    #pragma unroll
    for (int d = 0; d < ND; ++d)
        feat[d] = hidden[(size_t)b * NN * ND + (size_t)node * ND + d];
    const float* q = qw + r_index[b] * ND;
    #pragma unroll
    for (int d = 0; d < ND; ++d) feat[ND + d] = q[d];
    float acc2 = b2[0];
    for (int j = 0; j < 2 * ND; ++j) {
        float a = b1[j];
        #pragma unroll
        for (int kk = 0; kk < 2 * ND; ++kk) a += feat[kk] * w1[kk * 2 * ND + j];
        acc2 += fmaxf(a, 0.f) * w2[j];
    }
    out[i] = acc2;
}

extern "C" void kernel_launch(void* const* d_in, const int* in_sizes, int n_in,
                              void* d_out, int out_size, void* d_ws, size_t ws_size,
                              hipStream_t stream) {
    (void)in_sizes; (void)n_in; (void)out_size; (void)ws_size;
    const int* edge_index = (const int*)d_in[0];     // [2][E]
    const int* edge_type  = (const int*)d_in[1];     // [E]
    const int* h_index    = (const int*)d_in[2];     // [B]
    const int* r_index    = (const int*)d_in[3];     // [B]
    const int* t_index    = (const int*)d_in[4];     // [B][T]
    const float* query_weight = (const float*)d_in[5];  // [R][D]
    const float* rel_lin_w    = (const float*)d_in[6];  // [L][D][R*D]
    const float* layer_w      = (const float*)d_in[7];  // [L][13D][D]
    const float* layer_b      = (const float*)d_in[8];  // [L][D]
    const float* mlp_w1 = (const float*)d_in[9];
    const float* mlp_b1 = (const float*)d_in[10];
    const float* mlp_w2 = (const float*)d_in[11];
    const float* mlp_b2 = (const float*)d_in[12];
    float* out = (float*)d_out;

    const int* src = edge_index;
    const int* dst = edge_index + NE;

    char* wsp = (char*)d_ws;
    size_t off = 0;
    auto alloc = [&](size_t bytes) -> void* {
        void* p = wsp + off;
        off += (bytes + 255) & ~(size_t)255;
        return p;
    };
    float* h0      = (float*)alloc(sizeof(float) * M_TOT * ND);
    float* h1      = (float*)alloc(sizeof(float) * M_TOT * ND);
    float* At      = (float*)alloc(sizeof(float) * 160 * M_TOT);   // 51.2 MB
    float* rel     = (float*)alloc(sizeof(float) * NL * NB * NR * ND);
    int2*  csr     = (int2*)alloc(sizeof(int2) * NE);
    int*   offsets = (int*)alloc(sizeof(int) * (NN + 1));
    int*   cursor  = (int*)alloc(sizeof(int) * NN);
    int*   indeg   = (int*)alloc(sizeof(int) * NN);
    float* ssum    = (float*)alloc(256);

    hipMemsetAsync(indeg, 0, sizeof(int) * NN, stream);
    hipMemsetAsync(cursor, 0, sizeof(int) * NN, stream);
    hipMemsetAsync(ssum, 0, sizeof(float), stream);
    hipMemsetAsync(h0, 0, sizeof(float) * M_TOT * ND, stream);

    count_kernel<<<(NE + 255) / 256, 256, 0, stream>>>(dst, indeg);
    scan_kernel<<<1, 1024, 0, stream>>>(indeg, offsets);
    scatter_kernel<<<(NE + 255) / 256, 256, 0, stream>>>(src, dst, edge_type, offsets, cursor, csr);
    logsum_kernel<<<(NN + 255) / 256, 256, 0, stream>>>(indeg, ssum);
    init_hidden_kernel<<<1, NB * ND, 0, stream>>>(h0, h_index, r_index, query_weight);

    int rel_total = NL * NB * NR * ND;
    rel_kernel<<<(rel_total + 255) / 256, 256, 0, stream>>>(query_weight, r_index, rel_lin_w, rel);

    float* hin = h0;
    float* hout = h1;
    for (int l = 0; l < NL; ++l) {
        agg_kernel<<<M_TOT / 16, 512, 0, stream>>>(
            hin, At, rel + (size_t)l * NB * NR * ND,
            offsets, csr, h_index, r_index, query_weight);
        gemm_kernel<<<M_TOT / 128, 128, 0, stream>>>(
            At, hout, layer_w + (size_t)l * 13 * ND * ND, layer_b + (size_t)l * ND,
            offsets, ssum);
        float* t = hin; hin = hout; hout = t;
    }
    // final hidden is in `hin`

    score_kernel<<<1, 256, 0, stream>>>(hin, t_index, r_index, query_weight,
                                        mlp_w1, mlp_b1, mlp_w2, mlp_b2, out);
}